// Round 1
// baseline (3391.236 us; speedup 1.0000x reference)
//
#include <hip/hip_runtime.h>

// Problem: B=131072, P=3, D=128, H=4, DH=32  (fp32 in, fp32 out)
// out[b,q,d] = sum_f W_O[d,f] * z[b,q,f],  z from causal attention over P=3,
// q/k/v[b,i,p,h] = sum_d W_{Q,K,V}[i,h,d] * x[b,p,d]
//
// Round 1: fp32 VALU baseline (no fp32 MFMA on CDNA4). Fused single kernel,
// 8 batches (24 rows) per block, x + qkv staged in LDS (padded strides to
// avoid 64-way bank conflicts on the attention phase's column accesses).

#define BATCH_TOT 131072
#define PP 3
#define DD 128
#define HH 4
#define DHD 32
#define NQKV 384          // 3 * H * DH
#define BB 8              // batches per block
#define ROWS (BB * PP)    // 24
#define THREADS 256

// padded LDS strides (mod-32 != 0 in float units where scalar-accessed)
#define XS_STRIDE 132     // 128 + 4 (keeps 16B alignment for float4 rows)
#define QK_STRIDE 388     // 384 + 4

__global__ __launch_bounds__(THREADS)
void attn_fused_f32(const float* __restrict__ x,
                    const float* __restrict__ Wk,
                    const float* __restrict__ Wq,
                    const float* __restrict__ Wv,
                    const float* __restrict__ Wo,
                    float* __restrict__ out)
{
    __shared__ float xs[ROWS][XS_STRIDE];    // x tile; reused as z tile later
    __shared__ float qkvs[ROWS][QK_STRIDE];  // qkv tile

    const int t  = threadIdx.x;
    const int b0 = blockIdx.x * BB;

    // ---- stage x tile: 24 rows x 128 floats, coalesced float4 loads
    {
        const float4* xg = (const float4*)(x + (size_t)b0 * PP * DD);
        for (int i = t; i < ROWS * (DD / 4); i += THREADS) {
            int row = i >> 5;        // / (128/4)
            int c4  = i & 31;
            *(float4*)&xs[row][c4 * 4] = xg[(size_t)row * 32 + c4];
        }
    }
    __syncthreads();

    // ---- Phase A: qkv[24][384] = xs[24][128] * W^T
    // waves: rg = t>>6 owns rows rg*6..rg*6+5 ; ct = t&63 owns cols ct*6..+5
    {
        const int rg = t >> 6;
        const int ct = t & 63;
        float acc[6][6];
        #pragma unroll
        for (int i = 0; i < 6; ++i)
            #pragma unroll
            for (int j = 0; j < 6; ++j) acc[i][j] = 0.f;

        const float* wrow[6];
        #pragma unroll
        for (int j = 0; j < 6; ++j) {
            int n = ct * 6 + j;                       // 0..383
            const float* base = (n < 128) ? Wk : (n < 256 ? Wq : Wv);
            wrow[j] = base + (size_t)(n & 127) * DD;
        }

        for (int k = 0; k < DD; k += 4) {
            float4 w4[6];
            #pragma unroll
            for (int j = 0; j < 6; ++j) w4[j] = *(const float4*)(wrow[j] + k);
            #pragma unroll
            for (int i = 0; i < 6; ++i) {
                float4 x4 = *(const float4*)&xs[rg * 6 + i][k];
                #pragma unroll
                for (int j = 0; j < 6; ++j) {
                    acc[i][j] += x4.x * w4[j].x + x4.y * w4[j].y
                               + x4.z * w4[j].z + x4.w * w4[j].w;
                }
            }
        }
        #pragma unroll
        for (int i = 0; i < 6; ++i)
            #pragma unroll
            for (int j = 0; j < 6; ++j)
                qkvs[rg * 6 + i][ct * 6 + j] = acc[i][j];
    }
    __syncthreads();

    // ---- Phase B: attention, one thread per (local batch, head, qpos)
    // writes z into xs[row][i*32+h]  (x tile no longer needed)
    if (t < BB * HH * PP) {                     // 96 active threads
        const int lb  = t / (HH * PP);
        const int rem = t % (HH * PP);
        const int i   = rem / PP;
        const int q   = rem % PP;
        const int row_q = lb * PP + q;

        float qv[DHD];
        #pragma unroll
        for (int h = 0; h < DHD; ++h) qv[h] = qkvs[row_q][128 + i * DHD + h];

        float sc[PP];
        float m = -1e30f;
        for (int p = 0; p <= q; ++p) {
            float s = 0.f;
            #pragma unroll
            for (int h = 0; h < DHD; ++h)
                s += qkvs[lb * PP + p][i * DHD + h] * qv[h];
            s *= 0.17677669529663687f;          // 1/sqrt(32)
            sc[p] = s;
            m = fmaxf(m, s);
        }
        float l = 0.f;
        for (int p = 0; p <= q; ++p) { sc[p] = __expf(sc[p] - m); l += sc[p]; }
        const float inv = 1.f / l;

        #pragma unroll
        for (int h = 0; h < DHD; ++h) {
            float zv = 0.f;
            for (int p = 0; p <= q; ++p)
                zv += sc[p] * qkvs[lb * PP + p][256 + i * DHD + h];
            xs[row_q][i * DHD + h] = zv * inv;
        }
    }
    __syncthreads();

    // ---- Phase C: out[24][128] = z[24][128] * Wo^T
    // rg2 = t>>5 owns rows rg2*3..+2 ; ct2 = t&31 owns cols ct2*4..+3
    {
        const int rg2 = t >> 5;
        const int ct2 = t & 31;
        const int d0  = ct2 * 4;
        float acc[3][4];
        #pragma unroll
        for (int r = 0; r < 3; ++r)
            #pragma unroll
            for (int c = 0; c < 4; ++c) acc[r][c] = 0.f;

        for (int f = 0; f < DD; f += 4) {
            float4 wo4[4];
            #pragma unroll
            for (int c = 0; c < 4; ++c)
                wo4[c] = *(const float4*)&Wo[(size_t)(d0 + c) * DD + f];
            #pragma unroll
            for (int r = 0; r < 3; ++r) {
                float4 z4 = *(const float4*)&xs[rg2 * 3 + r][f];
                #pragma unroll
                for (int c = 0; c < 4; ++c) {
                    acc[r][c] += z4.x * wo4[c].x + z4.y * wo4[c].y
                               + z4.z * wo4[c].z + z4.w * wo4[c].w;
                }
            }
        }
        #pragma unroll
        for (int r = 0; r < 3; ++r) {
            size_t row_g = (size_t)b0 * PP + rg2 * 3 + r;
            float4 v = make_float4(acc[r][0], acc[r][1], acc[r][2], acc[r][3]);
            *(float4*)&out[row_g * DD + d0] = v;
        }
    }
}

extern "C" void kernel_launch(void* const* d_in, const int* in_sizes, int n_in,
                              void* d_out, int out_size, void* d_ws, size_t ws_size,
                              hipStream_t stream) {
    const float* x  = (const float*)d_in[0];
    const float* Wk = (const float*)d_in[1];
    const float* Wq = (const float*)d_in[2];
    const float* Wv = (const float*)d_in[3];
    const float* Wo = (const float*)d_in[4];
    float* out = (float*)d_out;

    const int grid = BATCH_TOT / BB;   // 16384
    attn_fused_f32<<<grid, THREADS, 0, stream>>>(x, Wk, Wq, Wv, Wo, out);
}

// Round 2
// 111.806 us; speedup vs baseline: 30.3313x; 30.3313x over previous
//
#include <hip/hip_runtime.h>

// B=131072, P=3, D=128, H=4, DH=32 ; fp32 in/out.
// Round 2: bf16-MFMA fused kernel.
//   pre-kernel: pack W_K|W_Q|W_V (384x128) and W_O (128x128) as bf16 MFMA
//               B-fragments into d_ws (131 KB, L2-resident).
//   main kernel (16 batches = 48 rows / block):
//     x fp32 -> bf16 LDS -> MFMA qkv GEMM (fp32 acc) -> bf16 qkv LDS
//     -> scalar fp32 causal attention (P=3) -> bf16 z LDS
//     -> MFMA out-proj -> fp32 global stores.
// mfma_f32_16x16x32_bf16 layouts (learn_hip m89-verified):
//   A: lane l holds A[l&15][(l>>4)*8 + j], j=0..7  (8 contiguous bf16)
//   B: lane l holds B[(l>>4)*8 + j][l&15]
//   C/D: col = l&15, row = (l>>4)*4 + reg

typedef __attribute__((ext_vector_type(8))) __bf16 bf16x8;
typedef __attribute__((ext_vector_type(4))) float f32x4;
typedef __attribute__((ext_vector_type(8))) unsigned short u16x8;

#define BATCH 131072
#define PP 3
#define DD 128
#define RB 48            // rows per block = 16 batches * 3
#define BB 16
#define THREADS 256
#define XS_STRIDE 136    // bf16 elements, 16B-aligned rows, stride%32 != 0
#define QS_STRIDE 392

#define NFRAG_QKV (24 * 4)   // 24 n-tiles x 4 k-steps
#define NFRAG_WO (8 * 4)
#define QKV_PACK_ELEMS (NFRAG_QKV * 64 * 8)   // 49152 bf16
#define WO_PACK_ELEMS (NFRAG_WO * 64 * 8)     // 16384 bf16

__device__ __forceinline__ unsigned short f2bf(float f) {
    unsigned int u = __float_as_uint(f);
    u = (u + 0x7fffu + ((u >> 16) & 1u)) >> 16;   // RNE
    return (unsigned short)u;
}
__device__ __forceinline__ float bf2f(unsigned short s) {
    return __uint_as_float(((unsigned int)s) << 16);
}

// ---- weight pre-pack: one thread per packed bf16 element -------------------
__global__ __launch_bounds__(256)
void pack_weights(const float* __restrict__ Wk, const float* __restrict__ Wq,
                  const float* __restrict__ Wv, const float* __restrict__ Wo,
                  unsigned short* __restrict__ pk)
{
    int e = blockIdx.x * 256 + threadIdx.x;     // 0 .. 65535
    int j = e & 7;
    int lane = (e >> 3) & 63;
    int lr = lane & 15, g = lane >> 4;
    float v;
    if (e < QKV_PACK_ELEMS) {
        int ks = (e >> 9) & 3;
        int nt = e >> 11;                        // 0..23
        int n = nt * 16 + lr;                    // qkv feature: 0..127 k, 128..255 q, 256..383 v
        int k = ks * 32 + g * 8 + j;             // d: 0..127
        const float* base = (n < 128) ? Wk : (n < 256 ? Wq : Wv);
        v = base[(size_t)(n & 127) * DD + k];
    } else {
        int e2 = e - QKV_PACK_ELEMS;
        int ks = (e2 >> 9) & 3;
        int nt = e2 >> 11;                       // 0..7
        int d = nt * 16 + lr;
        int f = ks * 32 + g * 8 + j;
        v = Wo[(size_t)d * DD + f];
    }
    pk[e] = f2bf(v);
}

// ---- fused attention --------------------------------------------------------
__global__ __launch_bounds__(THREADS)
void attn_mfma(const float* __restrict__ x,
               const unsigned short* __restrict__ wpk,
               float* __restrict__ out)
{
    __shared__ unsigned short xs[RB][XS_STRIDE];   // bf16 x, later bf16 z
    __shared__ unsigned short qk[RB][QS_STRIDE];   // bf16 qkv

    const int t = threadIdx.x;
    const int wave = t >> 6, lane = t & 63;
    const int lr = lane & 15, g = lane >> 4;
    const size_t row0 = (size_t)blockIdx.x * RB;

    // stage x: 48 rows x 128 fp32, coalesced float4, convert to bf16
    {
        const float4* xg = (const float4*)(x + row0 * DD);
        #pragma unroll
        for (int it = 0; it < 6; ++it) {
            int i = t + it * 256;                  // 0..1535
            float4 v = xg[i];
            int row = i >> 5, c = (i & 31) * 4;
            unsigned short b0 = f2bf(v.x), b1 = f2bf(v.y), b2 = f2bf(v.z), b3 = f2bf(v.w);
            xs[row][c]     = b0; xs[row][c + 1] = b1;
            xs[row][c + 2] = b2; xs[row][c + 3] = b3;
        }
    }
    __syncthreads();

    // Phase A: qkv[48][384] = x[48][128] @ W^T  (wave owns 6 n-tiles)
    {
        bf16x8 a[3][4];
        #pragma unroll
        for (int m = 0; m < 3; ++m)
            #pragma unroll
            for (int k = 0; k < 4; ++k)
                a[m][k] = *(const bf16x8*)&xs[m * 16 + lr][k * 32 + g * 8];

        const bf16x8* bp = (const bf16x8*)wpk;    // frag (nt*4+k)*64+lane
        const int ntb = wave * 6;
        bf16x8 bcur[4], bnxt[4];
        #pragma unroll
        for (int k = 0; k < 4; ++k) bcur[k] = bp[(ntb * 4 + k) * 64 + lane];

        const f32x4 zero4 = {0.f, 0.f, 0.f, 0.f};
        for (int n6 = 0; n6 < 6; ++n6) {
            int nt = ntb + n6;
            if (n6 < 5) {
                #pragma unroll
                for (int k = 0; k < 4; ++k) bnxt[k] = bp[((nt + 1) * 4 + k) * 64 + lane];
            }
            f32x4 acc[3];
            #pragma unroll
            for (int m = 0; m < 3; ++m) acc[m] = zero4;
            #pragma unroll
            for (int k = 0; k < 4; ++k)
                #pragma unroll
                for (int m = 0; m < 3; ++m)
                    acc[m] = __builtin_amdgcn_mfma_f32_16x16x32_bf16(a[m][k], bcur[k], acc[m], 0, 0, 0);
            #pragma unroll
            for (int m = 0; m < 3; ++m)
                #pragma unroll
                for (int r = 0; r < 4; ++r)
                    qk[m * 16 + g * 4 + r][nt * 16 + lr] = f2bf(acc[m][r]);
            if (n6 < 5) {
                #pragma unroll
                for (int k = 0; k < 4; ++k) bcur[k] = bnxt[k];
            }
        }
    }
    __syncthreads();

    // Phase B: causal attention, thread per (batch, head, qpos): 192 threads
    if (t < BB * 4 * PP) {
        const int lb = t / 12;
        const int rem = t % 12;
        const int hd = rem / 3;
        const int q = rem % 3;
        const int rq = lb * 3 + q;
        const int co = hd * 32;

        float qv[32];
        #pragma unroll
        for (int c = 0; c < 4; ++c) {
            u16x8 u = *(const u16x8*)&qk[rq][128 + co + c * 8];
            #pragma unroll
            for (int j = 0; j < 8; ++j) qv[c * 8 + j] = bf2f(u[j]);
        }
        float sc[3];
        float mx = -1e30f;
        #pragma unroll
        for (int p = 0; p < 3; ++p) {
            if (p <= q) {
                float s = 0.f;
                #pragma unroll
                for (int c = 0; c < 4; ++c) {
                    u16x8 u = *(const u16x8*)&qk[lb * 3 + p][co + c * 8];
                    #pragma unroll
                    for (int j = 0; j < 8; ++j) s += bf2f(u[j]) * qv[c * 8 + j];
                }
                s *= 0.17677669529663687f;        // 1/sqrt(32)
                sc[p] = s;
                mx = fmaxf(mx, s);
            }
        }
        float l = 0.f;
        #pragma unroll
        for (int p = 0; p < 3; ++p)
            if (p <= q) { sc[p] = __expf(sc[p] - mx); l += sc[p]; }
        const float inv = 1.f / l;

        #pragma unroll
        for (int c = 0; c < 4; ++c) {
            float z[8];
            #pragma unroll
            for (int j = 0; j < 8; ++j) z[j] = 0.f;
            #pragma unroll
            for (int p = 0; p < 3; ++p) {
                if (p <= q) {
                    u16x8 u = *(const u16x8*)&qk[lb * 3 + p][256 + co + c * 8];
                    #pragma unroll
                    for (int j = 0; j < 8; ++j) z[j] += sc[p] * bf2f(u[j]);
                }
            }
            u16x8 o;
            #pragma unroll
            for (int j = 0; j < 8; ++j) o[j] = f2bf(z[j] * inv);
            *(u16x8*)&xs[rq][co + c * 8] = o;     // z overwrites x tile
        }
    }
    __syncthreads();

    // Phase C: out[48][128] = z[48][128] @ Wo^T  (wave owns 2 n-tiles)
    {
        bf16x8 az[3][4];
        #pragma unroll
        for (int m = 0; m < 3; ++m)
            #pragma unroll
            for (int k = 0; k < 4; ++k)
                az[m][k] = *(const bf16x8*)&xs[m * 16 + lr][k * 32 + g * 8];

        const bf16x8* wop = (const bf16x8*)(wpk + QKV_PACK_ELEMS);
        const f32x4 zero4 = {0.f, 0.f, 0.f, 0.f};
        #pragma unroll
        for (int n2 = 0; n2 < 2; ++n2) {
            int nt = wave * 2 + n2;
            bf16x8 b[4];
            #pragma unroll
            for (int k = 0; k < 4; ++k) b[k] = wop[(nt * 4 + k) * 64 + lane];
            f32x4 acc[3];
            #pragma unroll
            for (int m = 0; m < 3; ++m) acc[m] = zero4;
            #pragma unroll
            for (int k = 0; k < 4; ++k)
                #pragma unroll
                for (int m = 0; m < 3; ++m)
                    acc[m] = __builtin_amdgcn_mfma_f32_16x16x32_bf16(az[m][k], b[k], acc[m], 0, 0, 0);
            #pragma unroll
            for (int m = 0; m < 3; ++m)
                #pragma unroll
                for (int r = 0; r < 4; ++r) {
                    size_t rg = row0 + (size_t)(m * 16 + g * 4 + r);
                    __builtin_nontemporal_store(acc[m][r], &out[rg * DD + nt * 16 + lr]);
                }
        }
    }
}

extern "C" void kernel_launch(void* const* d_in, const int* in_sizes, int n_in,
                              void* d_out, int out_size, void* d_ws, size_t ws_size,
                              hipStream_t stream) {
    const float* x  = (const float*)d_in[0];
    const float* Wk = (const float*)d_in[1];
    const float* Wq = (const float*)d_in[2];
    const float* Wv = (const float*)d_in[3];
    const float* Wo = (const float*)d_in[4];
    float* out = (float*)d_out;
    unsigned short* pk = (unsigned short*)d_ws;   // needs 131072 B

    pack_weights<<<(QKV_PACK_ELEMS + WO_PACK_ELEMS) / 256, 256, 0, stream>>>(Wk, Wq, Wv, Wo, pk);

    const int grid = BATCH * PP / RB;   // 8192
    attn_mfma<<<grid, THREADS, 0, stream>>>(x, pk, out);
}